// Round 1
// baseline (205.994 us; speedup 1.0000x reference)
//
#include <hip/hip_runtime.h>
#include <hip/hip_bf16.h>
#include <math.h>

// ---------------- model constants ----------------
#define T_LEN 1024
#define HID 1024
#define NHEAD 32
#define HDIM 64         // P
#define NSTATE 128      // N
#define NLVL 15
#define KCONV 4
#define INTER 2048
#define CONV_DIM 2304   // INTER + 2*N
#define PROJ 4864       // INTER + CONV_DIM + H*(NL+1)
#define NPROJ16 4352    // cols [0,4352) stored f16 (z | xBC), [4352,4864) f32 (dt | dl)
#define NPROJF 512      // PROJ - NPROJ16
#define EPS 1e-5f

typedef __attribute__((ext_vector_type(8))) _Float16 half8;
typedef __attribute__((ext_vector_type(4))) float float4v;
typedef unsigned short ushort_t;

__device__ __forceinline__ float softplus_f(float x) {
  return fmaxf(x, 0.f) + log1pf(expf(-fabsf(x)));
}
__device__ __forceinline__ float silu_f(float x) {
  return x / (1.f + expf(-x));
}
__device__ __forceinline__ ushort_t f2h(float f) {
  union { _Float16 h; ushort_t u; } v;
  v.h = (_Float16)f;
  return v.u;
}
__device__ __forceinline__ float h2f(ushort_t u) {
  union { ushort_t u; _Float16 h; } v;
  v.u = u;
  return (float)v.h;
}
// async global->LDS 16B: lds dst must be wave-uniform base; lane i lands at base+i*16
__device__ __forceinline__ void gload_lds16(const void* g, void* l) {
  __builtin_amdgcn_global_load_lds(
      (const __attribute__((address_space(1))) void*)g,
      (__attribute__((address_space(3))) void*)l, 16, 0, 0);
}

// ---------------- fused f32 -> f16 converts (hs, in_proj_w, out_proj_w) ----------------
#define N4_HS  (T_LEN * HID / 4)          // 262144
#define N4_WI  (PROJ * HID / 4)           // 1245184
#define N4_WO  (HID * INTER / 4)          // 524288
__global__ __launch_bounds__(256) void prep_f16(
    const float* __restrict__ hs, const float* __restrict__ wi,
    const float* __restrict__ wo, ushort_t* __restrict__ hsb,
    ushort_t* __restrict__ wib, ushort_t* __restrict__ wob) {
  int i = blockIdx.x * 256 + threadIdx.x;
  const float* src; ushort_t* dst; int j;
  if (i < N4_HS)              { src = hs; dst = hsb; j = i; }
  else if (i < N4_HS + N4_WI) { src = wi; dst = wib; j = i - N4_HS; }
  else                        { src = wo; dst = wob; j = i - N4_HS - N4_WI; }
  float4 v = reinterpret_cast<const float4*>(src)[j];
  union { ushort_t u[4]; unsigned long long ll; } o;
  o.u[0] = f2h(v.x); o.u[1] = f2h(v.y); o.u[2] = f2h(v.z); o.u[3] = f2h(v.w);
  reinterpret_cast<unsigned long long*>(dst)[j] = o.ll;
}

// ---------------- in_proj GEMM (K=1024, no split-K): bias folded, mixed f16/f32 store ----
// C[row][col] = sum_k A[row,k] * B[col,k] + bias[col]
// cols < 4352 -> zxh (f16), cols >= 4352 -> zxf (f32). Boundary 4352 = 34*128 (block-uniform).
__global__ __launch_bounds__(256) void gemm_in(
    const ushort_t* __restrict__ A, const ushort_t* __restrict__ B,
    const float* __restrict__ bias,
    ushort_t* __restrict__ Ch, float* __restrict__ Cf) {
  const int K = HID;
  __shared__ ushort_t As[2][128][32];   // 64B rows (no pad: global_load_lds layout)
  __shared__ ushort_t Bs[2][128][32];
  const int tid = threadIdx.x;
  const int w = tid >> 6, L = tid & 63;
  const int n0 = blockIdx.x * 128, m0 = blockIdx.y * 128;
  const int mq = (w & 1) * 64, nq = (w >> 1) * 64;
  const int srow = (L >> 2);
  const int sch = (L & 3) * 8;

  float4v acc[4][4];
#pragma unroll
  for (int i = 0; i < 4; ++i)
#pragma unroll
    for (int j = 0; j < 4; ++j) acc[i][j] = (float4v){0.f, 0.f, 0.f, 0.f};

  const int niter = K / 32;
  {
#pragma unroll
    for (int j = 0; j < 2; ++j) {
      int r0 = 16 * (w * 2 + j);
      gload_lds16(A + (size_t)(m0 + r0 + srow) * K + sch, &As[0][r0][0]);
      gload_lds16(B + (size_t)(n0 + r0 + srow) * K + sch, &Bs[0][r0][0]);
    }
  }
  for (int it = 0; it < niter; ++it) {
    __syncthreads();
    if (it + 1 < niter) {
      const int kk = (it + 1) * 32;
      const int nb = (it + 1) & 1;
#pragma unroll
      for (int j = 0; j < 2; ++j) {
        int r0 = 16 * (w * 2 + j);
        gload_lds16(A + (size_t)(m0 + r0 + srow) * K + kk + sch, &As[nb][r0][0]);
        gload_lds16(B + (size_t)(n0 + r0 + srow) * K + kk + sch, &Bs[nb][r0][0]);
      }
    }
    const int cb = it & 1;
    half8 af[4], bf[4];
#pragma unroll
    for (int t = 0; t < 4; ++t) {
      af[t] = *reinterpret_cast<const half8*>(&As[cb][mq + t * 16 + (L & 15)][(L >> 4) * 8]);
      bf[t] = *reinterpret_cast<const half8*>(&Bs[cb][nq + t * 16 + (L & 15)][(L >> 4) * 8]);
    }
#pragma unroll
    for (int mt = 0; mt < 4; ++mt)
#pragma unroll
      for (int nt = 0; nt < 4; ++nt)
        acc[mt][nt] = __builtin_amdgcn_mfma_f32_16x16x32_f16(af[mt], bf[nt], acc[mt][nt], 0, 0, 0);
  }
  const int qrow = (L >> 4) * 4;
  const bool tof16 = (n0 < NPROJ16);
#pragma unroll
  for (int mt = 0; mt < 4; ++mt) {
#pragma unroll
    for (int nt = 0; nt < 4; ++nt) {
      int col = n0 + nq + nt * 16 + (L & 15);
      float bv = bias[col];
#pragma unroll
      for (int r = 0; r < 4; ++r) {
        int row = m0 + mq + mt * 16 + qrow + r;
        float v = acc[mt][nt][r] + bv;
        if (tof16) Ch[(size_t)row * NPROJ16 + col] = f2h(v);
        else       Cf[(size_t)row * NPROJF + (col - NPROJ16)] = v;
      }
    }
  }
}

// ---------------- split-K f16 MFMA GEMM (dbuf + global_load_lds) for out_proj ----------
__global__ __launch_bounds__(256) void gemm_f16_sk(
    const ushort_t* __restrict__ A, const ushort_t* __restrict__ B,
    float* __restrict__ Cpart, int M, int N, int K, int Kc) {
  __shared__ ushort_t As[2][128][32];
  __shared__ ushort_t Bs[2][128][32];
  const int tid = threadIdx.x;
  const int w = tid >> 6, L = tid & 63;
  const int n0 = blockIdx.x * 128, m0 = blockIdx.y * 128;
  const int kbeg = blockIdx.z * Kc;
  float* __restrict__ C = Cpart + (size_t)blockIdx.z * M * N;
  const int mq = (w & 1) * 64, nq = (w >> 1) * 64;
  const int srow = (L >> 2);
  const int sch = (L & 3) * 8;

  float4v acc[4][4];
#pragma unroll
  for (int i = 0; i < 4; ++i)
#pragma unroll
    for (int j = 0; j < 4; ++j) acc[i][j] = (float4v){0.f, 0.f, 0.f, 0.f};

  const int niter = Kc / 32;
  {
    const int kk = kbeg;
#pragma unroll
    for (int j = 0; j < 2; ++j) {
      int r0 = 16 * (w * 2 + j);
      gload_lds16(A + (size_t)(m0 + r0 + srow) * K + kk + sch, &As[0][r0][0]);
      gload_lds16(B + (size_t)(n0 + r0 + srow) * K + kk + sch, &Bs[0][r0][0]);
    }
  }
  for (int it = 0; it < niter; ++it) {
    __syncthreads();
    if (it + 1 < niter) {
      const int kk = kbeg + (it + 1) * 32;
      const int nb = (it + 1) & 1;
#pragma unroll
      for (int j = 0; j < 2; ++j) {
        int r0 = 16 * (w * 2 + j);
        gload_lds16(A + (size_t)(m0 + r0 + srow) * K + kk + sch, &As[nb][r0][0]);
        gload_lds16(B + (size_t)(n0 + r0 + srow) * K + kk + sch, &Bs[nb][r0][0]);
      }
    }
    const int cb = it & 1;
    half8 af[4], bf[4];
#pragma unroll
    for (int t = 0; t < 4; ++t) {
      af[t] = *reinterpret_cast<const half8*>(&As[cb][mq + t * 16 + (L & 15)][(L >> 4) * 8]);
      bf[t] = *reinterpret_cast<const half8*>(&Bs[cb][nq + t * 16 + (L & 15)][(L >> 4) * 8]);
    }
#pragma unroll
    for (int mt = 0; mt < 4; ++mt)
#pragma unroll
      for (int nt = 0; nt < 4; ++nt)
        acc[mt][nt] = __builtin_amdgcn_mfma_f32_16x16x32_f16(af[mt], bf[nt], acc[mt][nt], 0, 0, 0);
  }
  const int qrow = (L >> 4) * 4;
#pragma unroll
  for (int mt = 0; mt < 4; ++mt) {
#pragma unroll
    for (int nt = 0; nt < 4; ++nt) {
      int col = n0 + nq + nt * 16 + (L & 15);
#pragma unroll
      for (int r = 0; r < 4; ++r) {
        int row = m0 + mq + mt * 16 + qrow + r;
        C[(size_t)row * N + col] = acc[mt][nt][r];
      }
    }
  }
}

// ---------------- reduce 4 out_proj partials + bias ----------------
__global__ __launch_bounds__(256) void reduce_out4(const float* __restrict__ p,
                                                   const float* __restrict__ bias,
                                                   float* __restrict__ out, int MN) {
  int i = blockIdx.x * 256 + threadIdx.x;
  if (i * 4 >= MN) return;
  float4 a = reinterpret_cast<const float4*>(p)[i];
  float4 b = reinterpret_cast<const float4*>(p + MN)[i];
  float4 c = reinterpret_cast<const float4*>(p + 2 * (size_t)MN)[i];
  float4 d = reinterpret_cast<const float4*>(p + 3 * (size_t)MN)[i];
  int col = (i * 4) & (HID - 1);
  float4 bv = *reinterpret_cast<const float4*>(bias + col);
  float4 o;
  o.x = a.x + b.x + c.x + d.x + bv.x;
  o.y = a.y + b.y + c.y + d.y + bv.y;
  o.z = a.z + b.z + c.z + d.z + bv.z;
  o.w = a.w + b.w + c.w + d.w + bv.w;
  reinterpret_cast<float4*>(out)[i] = o;
}

// ---------------- per-token pointwise: dt, g (transposed), level scales ----------------
// zxf holds pre-biased f32 cols [4352,4864): [dt(32) | dl(480)]
__global__ __launch_bounds__(512) void pointwise_dt(
    const float* __restrict__ zxf, const float* __restrict__ dt_bias,
    const float* __restrict__ A_log, const float* __restrict__ L_param,
    float* __restrict__ dtbuf, float* __restrict__ gT,
    float* __restrict__ Lsbuf) {
  const int t = blockIdx.x;
  const int j = threadIdx.x;
  const size_t ro = (size_t)t * NPROJF;
  if (j < NHEAD * NLVL) {
    float x = L_param[j] * zxf[ro + NHEAD + j];
    Lsbuf[(size_t)t * (NHEAD * NLVL) + j] = softplus_f(x);
  } else {
    int h = j - NHEAD * NLVL;
    float x = zxf[ro + h] + dt_bias[h];
    float dt = softplus_f(x);
    dtbuf[t * NHEAD + h] = dt;
    gT[h * T_LEN + t] = -expf(A_log[h]) * dt;   // transposed for the scan
  }
}

// ---------------- per-head fp64 scan, wave-shuffle (no barriers) ----------------
// grid = 32 heads, block = 64 lanes; lane l owns t in [l*16, l*16+16)
__global__ __launch_bounds__(64) void scan_g(const float* __restrict__ gT,
                                             double* __restrict__ cgd) {
  const int h = blockIdx.x, l = threadIdx.x;
  const float* gr = gT + (size_t)h * T_LEN + l * 16;
  double pre[16];
  double acc = 0.0;
#pragma unroll
  for (int i = 0; i < 16; ++i) { acc += (double)gr[i]; pre[i] = acc; }
  double s = acc;
#pragma unroll
  for (int off = 1; off < 64; off <<= 1) {
    double o = __shfl_up(s, off, 64);
    if (l >= off) s += o;
  }
  const double base = s - acc;   // exclusive prefix of lane totals
  double* cr = cgd + (size_t)h * T_LEN + l * 16;
#pragma unroll
  for (int i = 0; i < 16; ++i) cr[i] = base + pre[i];
}

// ---------------- fused conv(K=4)+SiLU+split, with in-block V transpose ----------------
// grid (16 t-tiles, 36 c-tiles of 64). c-tile<32: v path (head = cy); else B/C.
// xBC now read from zxh (f16, pre-biased) at cols [INTER, INTER+CONV_DIM)
__global__ __launch_bounds__(256) void conv_fused(
    const ushort_t* __restrict__ zxh, const float* __restrict__ conv_w,
    const float* __restrict__ dtbuf, const float* __restrict__ Dp,
    ushort_t* __restrict__ vt, float* __restrict__ ybuf,
    ushort_t* __restrict__ Bb, ushort_t* __restrict__ Cb) {
  __shared__ ushort_t Vl[64][68];
  __shared__ float dtl[64];
  const int tq = blockIdx.x, cy = blockIdx.y;
  const int t0 = tq * 64;
  const int tid = threadIdx.x;
  const int lane = tid & 63, g = tid >> 6;
  const bool vpath = (cy < 32);
  const int ccol = vpath ? cy * 64 + lane : INTER + (cy - 32) * 64 + lane;  // conv-dim idx
  const int zcol = INTER + ccol;   // column in zxh
  float cw[KCONV];
#pragma unroll
  for (int w = 0; w < KCONV; ++w) cw[w] = conv_w[ccol * KCONV + w];
  if (vpath && tid < 64) dtl[tid] = dtbuf[(t0 + tid) * NHEAD + cy];
  const float Dh = vpath ? Dp[cy] : 0.f;

  float xv[19];
#pragma unroll
  for (int i = 0; i < 19; ++i) {
    int tt = t0 + g * 16 - 3 + i;
    if (tt >= 0) {
      xv[i] = h2f(zxh[(size_t)tt * NPROJ16 + zcol]);
    } else xv[i] = 0.f;
  }
  __syncthreads();   // dtl ready
#pragma unroll
  for (int i = 0; i < 16; ++i) {
    float acc = xv[i] * cw[0] + xv[i + 1] * cw[1] + xv[i + 2] * cw[2] + xv[i + 3] * cw[3];
    float sil = silu_f(acc);
    int tl = g * 16 + i;
    int t = t0 + tl;
    if (vpath) {
      ushort_t vh = f2h(sil * dtl[tl]);
      Vl[tl][lane] = vh;                                       // for transpose
      ybuf[(size_t)t * INTER + cy * 64 + lane] = sil * Dh;     // D residual
    } else if (ccol < INTER + NSTATE) {
      Bb[t * NSTATE + (ccol - INTER)] = f2h(sil);
    } else {
      Cb[t * NSTATE + (ccol - INTER - NSTATE)] = f2h(sil);
    }
  }
  if (vpath) {
    __syncthreads();
#pragma unroll
    for (int rep = 0; rep < 2; ++rep) {
      int u = tid + 256 * rep;
      int p = u >> 3, t8 = (u & 7) * 8;
      union { ushort_t u16[8]; half8 h; } o;
#pragma unroll
      for (int j = 0; j < 8; ++j) o.u16[j] = Vl[t8 + j][p];
      *reinterpret_cast<half8*>(vt + (size_t)(cy * 64 + p) * T_LEN + t0 + t8) = o.h;
    }
  }
}

// ---------------- split-K MFMA attention ----------------
__global__ __launch_bounds__(256) void attn_mfma(
    const ushort_t* __restrict__ Bb, const ushort_t* __restrict__ Cb,
    const ushort_t* __restrict__ vt, const double* __restrict__ cgd,
    const float* __restrict__ Lsb, float* __restrict__ ybuf) {
  __shared__ ushort_t Bl[64][136];
  __shared__ ushort_t Vtl[64][72];
  __shared__ ushort_t Sl[64][72];
  __shared__ float Lsl[64][16];
  __shared__ float cgq[64];
  __shared__ float cgs[64];

  const int item = blockIdx.x;
  const int h = item / 40;
  const int rem = item - h * 40;
  int qt, j;
  if (rem < 4)        { qt = rem;                 j = 0; }
  else if (rem < 12)  { qt = 4 + (rem - 4) / 2;   j = (rem - 4) % 2; }
  else if (rem < 24)  { qt = 8 + (rem - 12) / 3;  j = (rem - 12) % 3; }
  else                { qt = 12 + (rem - 24) / 4; j = (rem - 24) % 4; }

  const int tid = threadIdx.x;
  const int w = tid >> 6, L = tid & 63;
  const int tq0 = qt * 64;
  const double* cgh = cgd + (size_t)h * T_LEN;
  const double base = cgh[tq0];

  for (int i = tid; i < 64 * NLVL; i += 256) {
    int r = i / NLVL, l = i - r * NLVL;
    Lsl[r][l] = Lsb[(size_t)(tq0 + r) * (NHEAD * NLVL) + h * NLVL + l];
  }
  if (tid < 64) cgq[tid] = (float)(cgh[tq0 + tid] - base);

  half8 cfrag[4];
  {
    const ushort_t* cr = Cb + (size_t)(tq0 + w * 16 + (L & 15)) * NSTATE + (L >> 4) * 8;
#pragma unroll
    for (int ks = 0; ks < 4; ++ks)
      cfrag[ks] = *reinterpret_cast<const half8*>(cr + ks * 32);
  }
  float4v yac[4];
#pragma unroll
  for (int i = 0; i < 4; ++i) yac[i] = (float4v){0.f, 0.f, 0.f, 0.f};

  const int qrow = w * 16 + ((L >> 4) << 2);

  const int st0 = 4 * j;
  const int st1 = min(4 * j + 4, qt + 1);
  for (int st = st0; st < st1; ++st) {
    const int ts0 = st * 64;
    __syncthreads();
#pragma unroll
    for (int i = 0; i < 4; ++i) {
      int u = tid + 256 * i;
      int row = u >> 4, kb = (u & 15) * 8;
      *reinterpret_cast<half8*>(&Bl[row][kb]) =
          *reinterpret_cast<const half8*>(Bb + (size_t)(ts0 + row) * NSTATE + kb);
    }
#pragma unroll
    for (int i = 0; i < 2; ++i) {
      int u = tid + 256 * i;
      int p = u >> 3, sc = (u & 7) * 8;
      *reinterpret_cast<half8*>(&Vtl[p][sc]) =
          *reinterpret_cast<const half8*>(vt + (size_t)(h * HDIM + p) * T_LEN + ts0 + sc);
    }
    if (tid < 64) cgs[tid] = (float)(cgh[ts0 + tid] - base);
    __syncthreads();

    float4v sac[4];
#pragma unroll
    for (int nt = 0; nt < 4; ++nt) sac[nt] = (float4v){0.f, 0.f, 0.f, 0.f};
#pragma unroll
    for (int ks = 0; ks < 4; ++ks) {
#pragma unroll
      for (int nt = 0; nt < 4; ++nt) {
        half8 bfrag = *reinterpret_cast<const half8*>(&Bl[nt * 16 + (L & 15)][ks * 32 + (L >> 4) * 8]);
        sac[nt] = __builtin_amdgcn_mfma_f32_16x16x32_f16(cfrag[ks], bfrag, sac[nt], 0, 0, 0);
      }
    }
#pragma unroll
    for (int nt = 0; nt < 4; ++nt) {
      int s = nt * 16 + (L & 15);
      int sg = ts0 + s;
      float cs = cgs[s];
#pragma unroll
      for (int r = 0; r < 4; ++r) {
        int q = qrow + r;
        int tg = tq0 + q;
        float val = 0.f;
        if (sg <= tg) {
          int lvl = 31 - __clz((unsigned)(sg ^ (tg + 1)));
          val = sac[nt][r] * __expf(cgq[q] - cs) * Lsl[q][lvl];
        }
        Sl[q][s] = f2h(val);
      }
    }
    __builtin_amdgcn_s_waitcnt(0);
#pragma unroll
    for (int ks = 0; ks < 2; ++ks) {
      half8 af = *reinterpret_cast<const half8*>(&Sl[w * 16 + (L & 15)][ks * 32 + (L >> 4) * 8]);
#pragma unroll
      for (int pt = 0; pt < 4; ++pt) {
        half8 bfv = *reinterpret_cast<const half8*>(&Vtl[pt * 16 + (L & 15)][ks * 32 + (L >> 4) * 8]);
        yac[pt] = __builtin_amdgcn_mfma_f32_16x16x32_f16(af, bfv, yac[pt], 0, 0, 0);
      }
    }
  }
#pragma unroll
  for (int pt = 0; pt < 4; ++pt) {
    int p = pt * 16 + (L & 15);
#pragma unroll
    for (int r = 0; r < 4; ++r) {
      int q = qrow + r;
      atomicAdd(ybuf + (size_t)(tq0 + q) * INTER + h * HDIM + p, yac[pt][r]);
    }
  }
}

// ---------------- gated RMSNorm -> f16 ----------------
// z read from zxh (f16, pre-biased) at cols [0, INTER)
__global__ __launch_bounds__(256) void rmsnorm_gate(
    const float* __restrict__ ybuf, const ushort_t* __restrict__ zxh,
    const float* __restrict__ w, ushort_t* __restrict__ yhf) {
  __shared__ float red[4];
  const int t = blockIdx.x, tid = threadIdx.x;
  const size_t ro = (size_t)t * NPROJ16;
  const float* yrow = ybuf + (size_t)t * INTER;
  float yg[8];
  float ss = 0.f;
#pragma unroll
  for (int i = 0; i < 8; ++i) {
    int c = tid + 256 * i;
    float z = h2f(zxh[ro + c]);
    float g = yrow[c] * silu_f(z);
    yg[i] = g;
    ss += g * g;
  }
#pragma unroll
  for (int off = 32; off; off >>= 1) ss += __shfl_down(ss, off, 64);
  if ((tid & 63) == 0) red[tid >> 6] = ss;
  __syncthreads();
  if (tid == 0) red[0] = red[0] + red[1] + red[2] + red[3];
  __syncthreads();
  const float scale = rsqrtf(red[0] / (float)INTER + EPS);
#pragma unroll
  for (int i = 0; i < 8; ++i) {
    int c = tid + 256 * i;
    yhf[(size_t)t * INTER + c] = f2h(yg[i] * scale * w[c]);
  }
}

// ---------------- launch ----------------
extern "C" void kernel_launch(void* const* d_in, const int* in_sizes, int n_in,
                              void* d_out, int out_size, void* d_ws, size_t ws_size,
                              hipStream_t stream) {
  const float* hs        = (const float*)d_in[0];
  const float* in_proj_w = (const float*)d_in[1];
  const float* in_proj_b = (const float*)d_in[2];
  const float* conv_w    = (const float*)d_in[3];
  const float* dt_bias   = (const float*)d_in[4];
  const float* A_log     = (const float*)d_in[5];
  const float* L_param   = (const float*)d_in[6];
  const float* Dp        = (const float*)d_in[7];
  const float* rms_w     = (const float*)d_in[8];
  const float* out_proj_w= (const float*)d_in[9];
  const float* out_proj_b= (const float*)d_in[10];
  float* out = (float*)d_out;

  char* W = (char*)d_ws;
  size_t off = 0;
  auto alloc = [&](size_t bytes) { void* p = W + off; off = (off + bytes + 255) & ~(size_t)255; return p; };
  double*   cgd = (double*)  alloc((size_t)NHEAD * T_LEN * 8);
  float*    zxf = (float*)   alloc((size_t)T_LEN * NPROJF * 4);
  float*    opp = (float*)   alloc((size_t)4 * T_LEN * HID * 4);
  float*    ybuf= (float*)   alloc((size_t)T_LEN * INTER * 4);
  float*    gT  = (float*)   alloc((size_t)NHEAD * T_LEN * 4);
  float*    dtb = (float*)   alloc((size_t)T_LEN * NHEAD * 4);
  float*    Lsb = (float*)   alloc((size_t)T_LEN * NHEAD * NLVL * 4);
  ushort_t* zxh = (ushort_t*)alloc((size_t)T_LEN * NPROJ16 * 2);
  ushort_t* hsb = (ushort_t*)alloc((size_t)T_LEN * HID * 2);
  ushort_t* Wib = (ushort_t*)alloc((size_t)PROJ * HID * 2);
  ushort_t* Wob = (ushort_t*)alloc((size_t)HID * INTER * 2);
  ushort_t* yhf = (ushort_t*)alloc((size_t)T_LEN * INTER * 2);
  ushort_t* vt  = (ushort_t*)alloc((size_t)T_LEN * INTER * 2);
  ushort_t* Bb  = (ushort_t*)alloc((size_t)T_LEN * NSTATE * 2);
  ushort_t* Cb  = (ushort_t*)alloc((size_t)T_LEN * NSTATE * 2);

  // 1. fused f32->f16 conversions (hs, in_proj_w, out_proj_w)
  prep_f16<<<(N4_HS + N4_WI + N4_WO) / 256, 256, 0, stream>>>(
      hs, in_proj_w, out_proj_w, hsb, Wib, Wob);

  // 2. in_proj GEMM: bias folded, mixed f16/f32 output, no split-K
  gemm_in<<<dim3(PROJ / 128, T_LEN / 128), 256, 0, stream>>>(
      hsb, Wib, in_proj_b, zxh, zxf);

  // 3. pointwise (g written transposed)
  pointwise_dt<<<T_LEN, 512, 0, stream>>>(zxf, dt_bias, A_log, L_param, dtb, gT, Lsb);

  // 4. fp64 wave-shuffle scan
  scan_g<<<NHEAD, 64, 0, stream>>>(gT, cgd);

  // 5. fused conv + silu + split + V transpose
  conv_fused<<<dim3(T_LEN / 64, 36), 256, 0, stream>>>(
      zxh, conv_w, dtb, Dp, vt, ybuf, Bb, Cb);

  // 6. split-K MFMA attention
  attn_mfma<<<NHEAD * 40, 256, 0, stream>>>(Bb, Cb, vt, cgd, Lsb, ybuf);

  // 7. gated RMSNorm -> f16
  rmsnorm_gate<<<T_LEN, 256, 0, stream>>>(ybuf, zxh, rms_w, yhf);

  // 8. out_proj split-K=4 -> partials, then reduce(+bias)
  gemm_f16_sk<<<dim3(HID / 128, T_LEN / 128, 4), 256, 0, stream>>>(
      yhf, Wob, opp, T_LEN, HID, INTER, INTER / 4);
  reduce_out4<<<(T_LEN * HID / 4 + 255) / 256, 256, 0, stream>>>(
      opp, out_proj_b, out, T_LEN * HID);
}

// Round 2
// 198.284 us; speedup vs baseline: 1.0389x; 1.0389x over previous
//
#include <hip/hip_runtime.h>
#include <hip/hip_bf16.h>
#include <math.h>

// ---------------- model constants ----------------
#define T_LEN 1024
#define HID 1024
#define NHEAD 32
#define HDIM 64         // P
#define NSTATE 128      // N
#define NLVL 15
#define KCONV 4
#define INTER 2048
#define CONV_DIM 2304   // INTER + 2*N
#define PROJ 4864       // INTER + CONV_DIM + H*(NL+1)
#define NPROJ16 4352    // cols [0,4352) stored f16 (z | xBC), [4352,4864) f32 (dt | dl)
#define NPROJF 512      // PROJ - NPROJ16
#define EPS 1e-5f

typedef __attribute__((ext_vector_type(8))) _Float16 half8;
typedef __attribute__((ext_vector_type(4))) float float4v;
typedef unsigned short ushort_t;

__device__ __forceinline__ float softplus_f(float x) {
  return fmaxf(x, 0.f) + log1pf(expf(-fabsf(x)));
}
__device__ __forceinline__ float silu_f(float x) {
  return x / (1.f + expf(-x));
}
__device__ __forceinline__ ushort_t f2h(float f) {
  union { _Float16 h; ushort_t u; } v;
  v.h = (_Float16)f;
  return v.u;
}
__device__ __forceinline__ float h2f(ushort_t u) {
  union { ushort_t u; _Float16 h; } v;
  v.u = u;
  return (float)v.h;
}
// async global->LDS 16B: lds dst must be wave-uniform base; lane i lands at base+i*16
__device__ __forceinline__ void gload_lds16(const void* g, void* l) {
  __builtin_amdgcn_global_load_lds(
      (const __attribute__((address_space(1))) void*)g,
      (__attribute__((address_space(3))) void*)l, 16, 0, 0);
}

// ---------------- fused f32 -> f16 converts (hs, in_proj_w, out_proj_w) ----------------
#define N4_HS  (T_LEN * HID / 4)          // 262144
#define N4_WI  (PROJ * HID / 4)           // 1245184
#define N4_WO  (HID * INTER / 4)          // 524288
__global__ __launch_bounds__(256) void prep_f16(
    const float* __restrict__ hs, const float* __restrict__ wi,
    const float* __restrict__ wo, ushort_t* __restrict__ hsb,
    ushort_t* __restrict__ wib, ushort_t* __restrict__ wob) {
  int i = blockIdx.x * 256 + threadIdx.x;
  const float* src; ushort_t* dst; int j;
  if (i < N4_HS)              { src = hs; dst = hsb; j = i; }
  else if (i < N4_HS + N4_WI) { src = wi; dst = wib; j = i - N4_HS; }
  else                        { src = wo; dst = wob; j = i - N4_HS - N4_WI; }
  float4 v = reinterpret_cast<const float4*>(src)[j];
  union { ushort_t u[4]; unsigned long long ll; } o;
  o.u[0] = f2h(v.x); o.u[1] = f2h(v.y); o.u[2] = f2h(v.z); o.u[3] = f2h(v.w);
  reinterpret_cast<unsigned long long*>(dst)[j] = o.ll;
}

// ---------------- in_proj GEMM (K=1024, full-K, 128x64 tiles): bias folded, mixed store --
// Grid 76 x 8 = 608 blocks (2.375 waves of 256 CUs) -> fine wave quantization without
// split-K partials. cols < 4352 -> zxh (f16), else zxf (f32); 4352 = 68*64, block-uniform.
__global__ __launch_bounds__(256) void gemm_in(
    const ushort_t* __restrict__ A, const ushort_t* __restrict__ B,
    const float* __restrict__ bias,
    ushort_t* __restrict__ Ch, float* __restrict__ Cf) {
  const int K = HID;
  __shared__ ushort_t As[2][128][32];   // 64B rows (no pad: global_load_lds layout)
  __shared__ ushort_t Bs[2][64][32];
  const int tid = threadIdx.x;
  const int w = tid >> 6, L = tid & 63;
  const int n0 = blockIdx.x * 64, m0 = blockIdx.y * 128;
  const int mq = (w & 1) * 64, nq = (w >> 1) * 32;   // wave: 64x32 sub-tile
  const int srow = (L >> 2);
  const int sch = (L & 3) * 8;

  float4v acc[4][2];
#pragma unroll
  for (int i = 0; i < 4; ++i)
#pragma unroll
    for (int j = 0; j < 2; ++j) acc[i][j] = (float4v){0.f, 0.f, 0.f, 0.f};

  const int niter = K / 32;
  {
    gload_lds16(A + (size_t)(m0 + 16 * w + srow) * K + sch, &As[0][16 * w][0]);
    gload_lds16(A + (size_t)(m0 + 64 + 16 * w + srow) * K + sch, &As[0][64 + 16 * w][0]);
    gload_lds16(B + (size_t)(n0 + 16 * w + srow) * K + sch, &Bs[0][16 * w][0]);
  }
  for (int it = 0; it < niter; ++it) {
    __syncthreads();
    if (it + 1 < niter) {
      const int kk = (it + 1) * 32;
      const int nb = (it + 1) & 1;
      gload_lds16(A + (size_t)(m0 + 16 * w + srow) * K + kk + sch, &As[nb][16 * w][0]);
      gload_lds16(A + (size_t)(m0 + 64 + 16 * w + srow) * K + kk + sch, &As[nb][64 + 16 * w][0]);
      gload_lds16(B + (size_t)(n0 + 16 * w + srow) * K + kk + sch, &Bs[nb][16 * w][0]);
    }
    const int cb = it & 1;
    half8 af[4], bf[2];
#pragma unroll
    for (int t = 0; t < 4; ++t)
      af[t] = *reinterpret_cast<const half8*>(&As[cb][mq + t * 16 + (L & 15)][(L >> 4) * 8]);
#pragma unroll
    for (int t = 0; t < 2; ++t)
      bf[t] = *reinterpret_cast<const half8*>(&Bs[cb][nq + t * 16 + (L & 15)][(L >> 4) * 8]);
#pragma unroll
    for (int mt = 0; mt < 4; ++mt)
#pragma unroll
      for (int nt = 0; nt < 2; ++nt)
        acc[mt][nt] = __builtin_amdgcn_mfma_f32_16x16x32_f16(af[mt], bf[nt], acc[mt][nt], 0, 0, 0);
  }
  const int qrow = (L >> 4) * 4;
  const bool tof16 = (n0 < NPROJ16);
#pragma unroll
  for (int mt = 0; mt < 4; ++mt) {
#pragma unroll
    for (int nt = 0; nt < 2; ++nt) {
      int col = n0 + nq + nt * 16 + (L & 15);
      float bv = bias[col];
#pragma unroll
      for (int r = 0; r < 4; ++r) {
        int row = m0 + mq + mt * 16 + qrow + r;
        float v = acc[mt][nt][r] + bv;
        if (tof16) Ch[(size_t)row * NPROJ16 + col] = f2h(v);
        else       Cf[(size_t)row * NPROJF + (col - NPROJ16)] = v;
      }
    }
  }
}

// ---------------- split-K f16 MFMA GEMM (dbuf + global_load_lds) for out_proj ----------
__global__ __launch_bounds__(256) void gemm_f16_sk(
    const ushort_t* __restrict__ A, const ushort_t* __restrict__ B,
    float* __restrict__ Cpart, int M, int N, int K, int Kc) {
  __shared__ ushort_t As[2][128][32];
  __shared__ ushort_t Bs[2][128][32];
  const int tid = threadIdx.x;
  const int w = tid >> 6, L = tid & 63;
  const int n0 = blockIdx.x * 128, m0 = blockIdx.y * 128;
  const int kbeg = blockIdx.z * Kc;
  float* __restrict__ C = Cpart + (size_t)blockIdx.z * M * N;
  const int mq = (w & 1) * 64, nq = (w >> 1) * 64;
  const int srow = (L >> 2);
  const int sch = (L & 3) * 8;

  float4v acc[4][4];
#pragma unroll
  for (int i = 0; i < 4; ++i)
#pragma unroll
    for (int j = 0; j < 4; ++j) acc[i][j] = (float4v){0.f, 0.f, 0.f, 0.f};

  const int niter = Kc / 32;
  {
    const int kk = kbeg;
#pragma unroll
    for (int j = 0; j < 2; ++j) {
      int r0 = 16 * (w * 2 + j);
      gload_lds16(A + (size_t)(m0 + r0 + srow) * K + kk + sch, &As[0][r0][0]);
      gload_lds16(B + (size_t)(n0 + r0 + srow) * K + kk + sch, &Bs[0][r0][0]);
    }
  }
  for (int it = 0; it < niter; ++it) {
    __syncthreads();
    if (it + 1 < niter) {
      const int kk = kbeg + (it + 1) * 32;
      const int nb = (it + 1) & 1;
#pragma unroll
      for (int j = 0; j < 2; ++j) {
        int r0 = 16 * (w * 2 + j);
        gload_lds16(A + (size_t)(m0 + r0 + srow) * K + kk + sch, &As[nb][r0][0]);
        gload_lds16(B + (size_t)(n0 + r0 + srow) * K + kk + sch, &Bs[nb][r0][0]);
      }
    }
    const int cb = it & 1;
    half8 af[4], bf[4];
#pragma unroll
    for (int t = 0; t < 4; ++t) {
      af[t] = *reinterpret_cast<const half8*>(&As[cb][mq + t * 16 + (L & 15)][(L >> 4) * 8]);
      bf[t] = *reinterpret_cast<const half8*>(&Bs[cb][nq + t * 16 + (L & 15)][(L >> 4) * 8]);
    }
#pragma unroll
    for (int mt = 0; mt < 4; ++mt)
#pragma unroll
      for (int nt = 0; nt < 4; ++nt)
        acc[mt][nt] = __builtin_amdgcn_mfma_f32_16x16x32_f16(af[mt], bf[nt], acc[mt][nt], 0, 0, 0);
  }
  const int qrow = (L >> 4) * 4;
#pragma unroll
  for (int mt = 0; mt < 4; ++mt) {
#pragma unroll
    for (int nt = 0; nt < 4; ++nt) {
      int col = n0 + nq + nt * 16 + (L & 15);
#pragma unroll
      for (int r = 0; r < 4; ++r) {
        int row = m0 + mq + mt * 16 + qrow + r;
        C[(size_t)row * N + col] = acc[mt][nt][r];
      }
    }
  }
}

// ---------------- reduce 4 out_proj partials + bias ----------------
__global__ __launch_bounds__(256) void reduce_out4(const float* __restrict__ p,
                                                   const float* __restrict__ bias,
                                                   float* __restrict__ out, int MN) {
  int i = blockIdx.x * 256 + threadIdx.x;
  if (i * 4 >= MN) return;
  float4 a = reinterpret_cast<const float4*>(p)[i];
  float4 b = reinterpret_cast<const float4*>(p + MN)[i];
  float4 c = reinterpret_cast<const float4*>(p + 2 * (size_t)MN)[i];
  float4 d = reinterpret_cast<const float4*>(p + 3 * (size_t)MN)[i];
  int col = (i * 4) & (HID - 1);
  float4 bv = *reinterpret_cast<const float4*>(bias + col);
  float4 o;
  o.x = a.x + b.x + c.x + d.x + bv.x;
  o.y = a.y + b.y + c.y + d.y + bv.y;
  o.z = a.z + b.z + c.z + d.z + bv.z;
  o.w = a.w + b.w + c.w + d.w + bv.w;
  reinterpret_cast<float4*>(out)[i] = o;
}

// ---------------- per-token pointwise: dt, g (transposed), level scales ----------------
// zxf holds pre-biased f32 cols [4352,4864): [dt(32) | dl(480)]
__global__ __launch_bounds__(512) void pointwise_dt(
    const float* __restrict__ zxf, const float* __restrict__ dt_bias,
    const float* __restrict__ A_log, const float* __restrict__ L_param,
    float* __restrict__ dtbuf, float* __restrict__ gT,
    float* __restrict__ Lsbuf) {
  const int t = blockIdx.x;
  const int j = threadIdx.x;
  const size_t ro = (size_t)t * NPROJF;
  if (j < NHEAD * NLVL) {
    float x = L_param[j] * zxf[ro + NHEAD + j];
    Lsbuf[(size_t)t * (NHEAD * NLVL) + j] = softplus_f(x);
  } else {
    int h = j - NHEAD * NLVL;
    float x = zxf[ro + h] + dt_bias[h];
    float dt = softplus_f(x);
    dtbuf[t * NHEAD + h] = dt;
    gT[h * T_LEN + t] = -expf(A_log[h]) * dt;   // transposed for the scan
  }
}

// ---------------- per-head fp64 scan, wave-shuffle (no barriers) ----------------
// grid = 32 heads, block = 64 lanes; lane l owns t in [l*16, l*16+16)
__global__ __launch_bounds__(64) void scan_g(const float* __restrict__ gT,
                                             double* __restrict__ cgd) {
  const int h = blockIdx.x, l = threadIdx.x;
  const float* gr = gT + (size_t)h * T_LEN + l * 16;
  double pre[16];
  double acc = 0.0;
#pragma unroll
  for (int i = 0; i < 16; ++i) { acc += (double)gr[i]; pre[i] = acc; }
  double s = acc;
#pragma unroll
  for (int off = 1; off < 64; off <<= 1) {
    double o = __shfl_up(s, off, 64);
    if (l >= off) s += o;
  }
  const double base = s - acc;   // exclusive prefix of lane totals
  double* cr = cgd + (size_t)h * T_LEN + l * 16;
#pragma unroll
  for (int i = 0; i < 16; ++i) cr[i] = base + pre[i];
}

// ---------------- fused conv(K=4)+SiLU+split, with in-block V transpose ----------------
// grid (16 t-tiles, 36 c-tiles of 64). c-tile<32: v path (head = cy); else B/C.
// xBC read from zxh (f16, pre-biased) at cols [INTER, INTER+CONV_DIM)
__global__ __launch_bounds__(256) void conv_fused(
    const ushort_t* __restrict__ zxh, const float* __restrict__ conv_w,
    const float* __restrict__ dtbuf, const float* __restrict__ Dp,
    ushort_t* __restrict__ vt, float* __restrict__ ybuf,
    ushort_t* __restrict__ Bb, ushort_t* __restrict__ Cb) {
  __shared__ ushort_t Vl[64][68];
  __shared__ float dtl[64];
  const int tq = blockIdx.x, cy = blockIdx.y;
  const int t0 = tq * 64;
  const int tid = threadIdx.x;
  const int lane = tid & 63, g = tid >> 6;
  const bool vpath = (cy < 32);
  const int ccol = vpath ? cy * 64 + lane : INTER + (cy - 32) * 64 + lane;  // conv-dim idx
  const int zcol = INTER + ccol;   // column in zxh
  float cw[KCONV];
#pragma unroll
  for (int w = 0; w < KCONV; ++w) cw[w] = conv_w[ccol * KCONV + w];
  if (vpath && tid < 64) dtl[tid] = dtbuf[(t0 + tid) * NHEAD + cy];
  const float Dh = vpath ? Dp[cy] : 0.f;

  float xv[19];
#pragma unroll
  for (int i = 0; i < 19; ++i) {
    int tt = t0 + g * 16 - 3 + i;
    if (tt >= 0) {
      xv[i] = h2f(zxh[(size_t)tt * NPROJ16 + zcol]);
    } else xv[i] = 0.f;
  }
  __syncthreads();   // dtl ready
#pragma unroll
  for (int i = 0; i < 16; ++i) {
    float acc = xv[i] * cw[0] + xv[i + 1] * cw[1] + xv[i + 2] * cw[2] + xv[i + 3] * cw[3];
    float sil = silu_f(acc);
    int tl = g * 16 + i;
    int t = t0 + tl;
    if (vpath) {
      ushort_t vh = f2h(sil * dtl[tl]);
      Vl[tl][lane] = vh;                                       // for transpose
      ybuf[(size_t)t * INTER + cy * 64 + lane] = sil * Dh;     // D residual
    } else if (ccol < INTER + NSTATE) {
      Bb[t * NSTATE + (ccol - INTER)] = f2h(sil);
    } else {
      Cb[t * NSTATE + (ccol - INTER - NSTATE)] = f2h(sil);
    }
  }
  if (vpath) {
    __syncthreads();
#pragma unroll
    for (int rep = 0; rep < 2; ++rep) {
      int u = tid + 256 * rep;
      int p = u >> 3, t8 = (u & 7) * 8;
      union { ushort_t u16[8]; half8 h; } o;
#pragma unroll
      for (int j = 0; j < 8; ++j) o.u16[j] = Vl[t8 + j][p];
      *reinterpret_cast<half8*>(vt + (size_t)(cy * 64 + p) * T_LEN + t0 + t8) = o.h;
    }
  }
}

// ---------------- split-K MFMA attention ----------------
__global__ __launch_bounds__(256) void attn_mfma(
    const ushort_t* __restrict__ Bb, const ushort_t* __restrict__ Cb,
    const ushort_t* __restrict__ vt, const double* __restrict__ cgd,
    const float* __restrict__ Lsb, float* __restrict__ ybuf) {
  __shared__ ushort_t Bl[64][136];
  __shared__ ushort_t Vtl[64][72];
  __shared__ ushort_t Sl[64][72];
  __shared__ float Lsl[64][16];
  __shared__ float cgq[64];
  __shared__ float cgs[64];

  const int item = blockIdx.x;
  const int h = item / 40;
  const int rem = item - h * 40;
  int qt, j;
  if (rem < 4)        { qt = rem;                 j = 0; }
  else if (rem < 12)  { qt = 4 + (rem - 4) / 2;   j = (rem - 4) % 2; }
  else if (rem < 24)  { qt = 8 + (rem - 12) / 3;  j = (rem - 12) % 3; }
  else                { qt = 12 + (rem - 24) / 4; j = (rem - 24) % 4; }

  const int tid = threadIdx.x;
  const int w = tid >> 6, L = tid & 63;
  const int tq0 = qt * 64;
  const double* cgh = cgd + (size_t)h * T_LEN;
  const double base = cgh[tq0];

  for (int i = tid; i < 64 * NLVL; i += 256) {
    int r = i / NLVL, l = i - r * NLVL;
    Lsl[r][l] = Lsb[(size_t)(tq0 + r) * (NHEAD * NLVL) + h * NLVL + l];
  }
  if (tid < 64) cgq[tid] = (float)(cgh[tq0 + tid] - base);

  half8 cfrag[4];
  {
    const ushort_t* cr = Cb + (size_t)(tq0 + w * 16 + (L & 15)) * NSTATE + (L >> 4) * 8;
#pragma unroll
    for (int ks = 0; ks < 4; ++ks)
      cfrag[ks] = *reinterpret_cast<const half8*>(cr + ks * 32);
  }
  float4v yac[4];
#pragma unroll
  for (int i = 0; i < 4; ++i) yac[i] = (float4v){0.f, 0.f, 0.f, 0.f};

  const int qrow = w * 16 + ((L >> 4) << 2);

  const int st0 = 4 * j;
  const int st1 = min(4 * j + 4, qt + 1);
  for (int st = st0; st < st1; ++st) {
    const int ts0 = st * 64;
    __syncthreads();
#pragma unroll
    for (int i = 0; i < 4; ++i) {
      int u = tid + 256 * i;
      int row = u >> 4, kb = (u & 15) * 8;
      *reinterpret_cast<half8*>(&Bl[row][kb]) =
          *reinterpret_cast<const half8*>(Bb + (size_t)(ts0 + row) * NSTATE + kb);
    }
#pragma unroll
    for (int i = 0; i < 2; ++i) {
      int u = tid + 256 * i;
      int p = u >> 3, sc = (u & 7) * 8;
      *reinterpret_cast<half8*>(&Vtl[p][sc]) =
          *reinterpret_cast<const half8*>(vt + (size_t)(h * HDIM + p) * T_LEN + ts0 + sc);
    }
    if (tid < 64) cgs[tid] = (float)(cgh[ts0 + tid] - base);
    __syncthreads();

    float4v sac[4];
#pragma unroll
    for (int nt = 0; nt < 4; ++nt) sac[nt] = (float4v){0.f, 0.f, 0.f, 0.f};
#pragma unroll
    for (int ks = 0; ks < 4; ++ks) {
#pragma unroll
      for (int nt = 0; nt < 4; ++nt) {
        half8 bfrag = *reinterpret_cast<const half8*>(&Bl[nt * 16 + (L & 15)][ks * 32 + (L >> 4) * 8]);
        sac[nt] = __builtin_amdgcn_mfma_f32_16x16x32_f16(cfrag[ks], bfrag, sac[nt], 0, 0, 0);
      }
    }
#pragma unroll
    for (int nt = 0; nt < 4; ++nt) {
      int s = nt * 16 + (L & 15);
      int sg = ts0 + s;
      float cs = cgs[s];
#pragma unroll
      for (int r = 0; r < 4; ++r) {
        int q = qrow + r;
        int tg = tq0 + q;
        float val = 0.f;
        if (sg <= tg) {
          int lvl = 31 - __clz((unsigned)(sg ^ (tg + 1)));
          val = sac[nt][r] * __expf(cgq[q] - cs) * Lsl[q][lvl];
        }
        Sl[q][s] = f2h(val);
      }
    }
    __builtin_amdgcn_s_waitcnt(0);
#pragma unroll
    for (int ks = 0; ks < 2; ++ks) {
      half8 af = *reinterpret_cast<const half8*>(&Sl[w * 16 + (L & 15)][ks * 32 + (L >> 4) * 8]);
#pragma unroll
      for (int pt = 0; pt < 4; ++pt) {
        half8 bfv = *reinterpret_cast<const half8*>(&Vtl[pt * 16 + (L & 15)][ks * 32 + (L >> 4) * 8]);
        yac[pt] = __builtin_amdgcn_mfma_f32_16x16x32_f16(af, bfv, yac[pt], 0, 0, 0);
      }
    }
  }
#pragma unroll
  for (int pt = 0; pt < 4; ++pt) {
    int p = pt * 16 + (L & 15);
#pragma unroll
    for (int r = 0; r < 4; ++r) {
      int q = qrow + r;
      atomicAdd(ybuf + (size_t)(tq0 + q) * INTER + h * HDIM + p, yac[pt][r]);
    }
  }
}

// ---------------- gated RMSNorm -> f16 ----------------
// z read from zxh (f16, pre-biased) at cols [0, INTER)
__global__ __launch_bounds__(256) void rmsnorm_gate(
    const float* __restrict__ ybuf, const ushort_t* __restrict__ zxh,
    const float* __restrict__ w, ushort_t* __restrict__ yhf) {
  __shared__ float red[4];
  const int t = blockIdx.x, tid = threadIdx.x;
  const size_t ro = (size_t)t * NPROJ16;
  const float* yrow = ybuf + (size_t)t * INTER;
  float yg[8];
  float ss = 0.f;
#pragma unroll
  for (int i = 0; i < 8; ++i) {
    int c = tid + 256 * i;
    float z = h2f(zxh[ro + c]);
    float g = yrow[c] * silu_f(z);
    yg[i] = g;
    ss += g * g;
  }
#pragma unroll
  for (int off = 32; off; off >>= 1) ss += __shfl_down(ss, off, 64);
  if ((tid & 63) == 0) red[tid >> 6] = ss;
  __syncthreads();
  if (tid == 0) red[0] = red[0] + red[1] + red[2] + red[3];
  __syncthreads();
  const float scale = rsqrtf(red[0] / (float)INTER + EPS);
#pragma unroll
  for (int i = 0; i < 8; ++i) {
    int c = tid + 256 * i;
    yhf[(size_t)t * INTER + c] = f2h(yg[i] * scale * w[c]);
  }
}

// ---------------- launch ----------------
extern "C" void kernel_launch(void* const* d_in, const int* in_sizes, int n_in,
                              void* d_out, int out_size, void* d_ws, size_t ws_size,
                              hipStream_t stream) {
  const float* hs        = (const float*)d_in[0];
  const float* in_proj_w = (const float*)d_in[1];
  const float* in_proj_b = (const float*)d_in[2];
  const float* conv_w    = (const float*)d_in[3];
  const float* dt_bias   = (const float*)d_in[4];
  const float* A_log     = (const float*)d_in[5];
  const float* L_param   = (const float*)d_in[6];
  const float* Dp        = (const float*)d_in[7];
  const float* rms_w     = (const float*)d_in[8];
  const float* out_proj_w= (const float*)d_in[9];
  const float* out_proj_b= (const float*)d_in[10];
  float* out = (float*)d_out;

  char* W = (char*)d_ws;
  size_t off = 0;
  auto alloc = [&](size_t bytes) { void* p = W + off; off = (off + bytes + 255) & ~(size_t)255; return p; };
  double*   cgd = (double*)  alloc((size_t)NHEAD * T_LEN * 8);
  float*    zxf = (float*)   alloc((size_t)T_LEN * NPROJF * 4);
  float*    opp = (float*)   alloc((size_t)4 * T_LEN * HID * 4);
  float*    ybuf= (float*)   alloc((size_t)T_LEN * INTER * 4);
  float*    gT  = (float*)   alloc((size_t)NHEAD * T_LEN * 4);
  float*    dtb = (float*)   alloc((size_t)T_LEN * NHEAD * 4);
  float*    Lsb = (float*)   alloc((size_t)T_LEN * NHEAD * NLVL * 4);
  ushort_t* zxh = (ushort_t*)alloc((size_t)T_LEN * NPROJ16 * 2);
  ushort_t* hsb = (ushort_t*)alloc((size_t)T_LEN * HID * 2);
  ushort_t* Wib = (ushort_t*)alloc((size_t)PROJ * HID * 2);
  ushort_t* Wob = (ushort_t*)alloc((size_t)HID * INTER * 2);
  ushort_t* yhf = (ushort_t*)alloc((size_t)T_LEN * INTER * 2);
  ushort_t* vt  = (ushort_t*)alloc((size_t)T_LEN * INTER * 2);
  ushort_t* Bb  = (ushort_t*)alloc((size_t)T_LEN * NSTATE * 2);
  ushort_t* Cb  = (ushort_t*)alloc((size_t)T_LEN * NSTATE * 2);

  // 1. fused f32->f16 conversions (hs, in_proj_w, out_proj_w)
  prep_f16<<<(N4_HS + N4_WI + N4_WO) / 256, 256, 0, stream>>>(
      hs, in_proj_w, out_proj_w, hsb, Wib, Wob);

  // 2. in_proj GEMM: bias folded, mixed f16/f32 output, 128x64 tiles (608 blocks)
  gemm_in<<<dim3(PROJ / 64, T_LEN / 128), 256, 0, stream>>>(
      hsb, Wib, in_proj_b, zxh, zxf);

  // 3. pointwise (g written transposed)
  pointwise_dt<<<T_LEN, 512, 0, stream>>>(zxf, dt_bias, A_log, L_param, dtb, gT, Lsb);

  // 4. fp64 wave-shuffle scan
  scan_g<<<NHEAD, 64, 0, stream>>>(gT, cgd);

  // 5. fused conv + silu + split + V transpose
  conv_fused<<<dim3(T_LEN / 64, 36), 256, 0, stream>>>(
      zxh, conv_w, dtb, Dp, vt, ybuf, Bb, Cb);

  // 6. split-K MFMA attention
  attn_mfma<<<NHEAD * 40, 256, 0, stream>>>(Bb, Cb, vt, cgd, Lsb, ybuf);

  // 7. gated RMSNorm -> f16
  rmsnorm_gate<<<T_LEN, 256, 0, stream>>>(ybuf, zxh, rms_w, yhf);

  // 8. out_proj split-K=4 -> partials, then reduce(+bias)
  gemm_f16_sk<<<dim3(HID / 128, T_LEN / 128, 4), 256, 0, stream>>>(
      yhf, Wob, opp, T_LEN, HID, INTER, INTER / 4);
  reduce_out4<<<(T_LEN * HID / 4 + 255) / 256, 256, 0, stream>>>(
      opp, out_proj_b, out, T_LEN * HID);
}

// Round 3
// 191.459 us; speedup vs baseline: 1.0759x; 1.0356x over previous
//
#include <hip/hip_runtime.h>
#include <hip/hip_bf16.h>
#include <math.h>

// ---------------- model constants ----------------
#define T_LEN 1024
#define HID 1024
#define NHEAD 32
#define HDIM 64         // P
#define NSTATE 128      // N
#define NLVL 15
#define KCONV 4
#define INTER 2048
#define CONV_DIM 2304   // INTER + 2*N
#define PROJ 4864       // INTER + CONV_DIM + H*(NL+1)
#define NPROJ16 4352    // cols [0,4352) stored f16 (z | xBC), [4352,4864) f32 (dt | dl)
#define NPROJF 512      // PROJ - NPROJ16
#define EPS 1e-5f

typedef __attribute__((ext_vector_type(8))) _Float16 half8;
typedef __attribute__((ext_vector_type(4))) float float4v;
typedef unsigned short ushort_t;

__device__ __forceinline__ float softplus_f(float x) {
  return fmaxf(x, 0.f) + log1pf(expf(-fabsf(x)));
}
__device__ __forceinline__ float silu_f(float x) {
  return x / (1.f + expf(-x));
}
__device__ __forceinline__ ushort_t f2h(float f) {
  union { _Float16 h; ushort_t u; } v;
  v.h = (_Float16)f;
  return v.u;
}
__device__ __forceinline__ float h2f(ushort_t u) {
  union { ushort_t u; _Float16 h; } v;
  v.u = u;
  return (float)v.h;
}
// async global->LDS 16B: lds dst must be wave-uniform base; lane i lands at base+i*16
__device__ __forceinline__ void gload_lds16(const void* g, void* l) {
  __builtin_amdgcn_global_load_lds(
      (const __attribute__((address_space(1))) void*)g,
      (__attribute__((address_space(3))) void*)l, 16, 0, 0);
}

// ---------------- fused f32 -> f16 converts (hs, in_proj_w, out_proj_w) ----------------
#define N4_HS  (T_LEN * HID / 4)          // 262144
#define N4_WI  (PROJ * HID / 4)           // 1245184
#define N4_WO  (HID * INTER / 4)          // 524288
__global__ __launch_bounds__(256) void prep_f16(
    const float* __restrict__ hs, const float* __restrict__ wi,
    const float* __restrict__ wo, ushort_t* __restrict__ hsb,
    ushort_t* __restrict__ wib, ushort_t* __restrict__ wob) {
  int i = blockIdx.x * 256 + threadIdx.x;
  const float* src; ushort_t* dst; int j;
  if (i < N4_HS)              { src = hs; dst = hsb; j = i; }
  else if (i < N4_HS + N4_WI) { src = wi; dst = wib; j = i - N4_HS; }
  else                        { src = wo; dst = wob; j = i - N4_HS - N4_WI; }
  float4 v = reinterpret_cast<const float4*>(src)[j];
  union { ushort_t u[4]; unsigned long long ll; } o;
  o.u[0] = f2h(v.x); o.u[1] = f2h(v.y); o.u[2] = f2h(v.z); o.u[3] = f2h(v.w);
  reinterpret_cast<unsigned long long*>(dst)[j] = o.ll;
}

// ---------------- in_proj GEMM (128x128 tile, full-K, BK=64, XOR-swizzled LDS) ---------
// Grid 38 x 8 = 304 blocks, 16 fat iterations (32 MFMA/wave/iter).
// LDS rows are 128B -> staging source chunk is XOR-swizzled by (row&7); reads XOR back.
// cols < 4352 -> zxh (f16), else zxf (f32); 4352 = 34*128, block-uniform.
__global__ __launch_bounds__(256) void gemm_in(
    const ushort_t* __restrict__ A, const ushort_t* __restrict__ B,
    const float* __restrict__ bias,
    ushort_t* __restrict__ Ch, float* __restrict__ Cf) {
  const int K = HID;
  __shared__ ushort_t As[2][128][64];
  __shared__ ushort_t Bs[2][128][64];
  const int tid = threadIdx.x;
  const int w = tid >> 6, L = tid & 63;
  const int n0 = blockIdx.x * 128, m0 = blockIdx.y * 128;
  const int mq = (w & 1) * 64, nq = (w >> 1) * 64;
  const int srow = L >> 3;                 // 0..7 within the 8-row 1KB chunk
  const int swst = ((L & 7) ^ srow) * 8;   // swizzled source f16-col

  float4v acc[4][4];
#pragma unroll
  for (int i = 0; i < 4; ++i)
#pragma unroll
    for (int j = 0; j < 4; ++j) acc[i][j] = (float4v){0.f, 0.f, 0.f, 0.f};

  const int niter = K / 64;
  {
#pragma unroll
    for (int j = 0; j < 4; ++j) {
      int r0 = 8 * (w * 4 + j);
      gload_lds16(A + (size_t)(m0 + r0 + srow) * K + swst, &As[0][r0][0]);
      gload_lds16(B + (size_t)(n0 + r0 + srow) * K + swst, &Bs[0][r0][0]);
    }
  }
  for (int it = 0; it < niter; ++it) {
    __syncthreads();
    if (it + 1 < niter) {
      const int kk = (it + 1) * 64;
      const int nb = (it + 1) & 1;
#pragma unroll
      for (int j = 0; j < 4; ++j) {
        int r0 = 8 * (w * 4 + j);
        gload_lds16(A + (size_t)(m0 + r0 + srow) * K + kk + swst, &As[nb][r0][0]);
        gload_lds16(B + (size_t)(n0 + r0 + srow) * K + kk + swst, &Bs[nb][r0][0]);
      }
    }
    const int cb = it & 1;
    half8 af[4][2], bf[4][2];
#pragma unroll
    for (int kk2 = 0; kk2 < 2; ++kk2) {
      const int sw = ((kk2 * 4 + (L >> 4)) ^ (L & 7)) * 8;
#pragma unroll
      for (int t = 0; t < 4; ++t) {
        af[t][kk2] = *reinterpret_cast<const half8*>(&As[cb][mq + t * 16 + (L & 15)][sw]);
        bf[t][kk2] = *reinterpret_cast<const half8*>(&Bs[cb][nq + t * 16 + (L & 15)][sw]);
      }
    }
#pragma unroll
    for (int kk2 = 0; kk2 < 2; ++kk2)
#pragma unroll
      for (int mt = 0; mt < 4; ++mt)
#pragma unroll
        for (int nt = 0; nt < 4; ++nt)
          acc[mt][nt] = __builtin_amdgcn_mfma_f32_16x16x32_f16(af[mt][kk2], bf[nt][kk2],
                                                               acc[mt][nt], 0, 0, 0);
  }
  const int qrow = (L >> 4) * 4;
  const bool tof16 = (n0 < NPROJ16);
#pragma unroll
  for (int mt = 0; mt < 4; ++mt) {
#pragma unroll
    for (int nt = 0; nt < 4; ++nt) {
      int col = n0 + nq + nt * 16 + (L & 15);
      float bv = bias[col];
#pragma unroll
      for (int r = 0; r < 4; ++r) {
        int row = m0 + mq + mt * 16 + qrow + r;
        float v = acc[mt][nt][r] + bv;
        if (tof16) Ch[(size_t)row * NPROJ16 + col] = f2h(v);
        else       Cf[(size_t)row * NPROJF + (col - NPROJ16)] = v;
      }
    }
  }
}

// ---------------- split-K f16 MFMA GEMM (BK=64, swizzled) for out_proj ----------------
__global__ __launch_bounds__(256) void gemm_f16_sk(
    const ushort_t* __restrict__ A, const ushort_t* __restrict__ B,
    float* __restrict__ Cpart, int M, int N, int K, int Kc) {
  __shared__ ushort_t As[2][128][64];
  __shared__ ushort_t Bs[2][128][64];
  const int tid = threadIdx.x;
  const int w = tid >> 6, L = tid & 63;
  const int n0 = blockIdx.x * 128, m0 = blockIdx.y * 128;
  const int kbeg = blockIdx.z * Kc;
  float* __restrict__ C = Cpart + (size_t)blockIdx.z * M * N;
  const int mq = (w & 1) * 64, nq = (w >> 1) * 64;
  const int srow = L >> 3;
  const int swst = ((L & 7) ^ srow) * 8;

  float4v acc[4][4];
#pragma unroll
  for (int i = 0; i < 4; ++i)
#pragma unroll
    for (int j = 0; j < 4; ++j) acc[i][j] = (float4v){0.f, 0.f, 0.f, 0.f};

  const int niter = Kc / 64;
  {
#pragma unroll
    for (int j = 0; j < 4; ++j) {
      int r0 = 8 * (w * 4 + j);
      gload_lds16(A + (size_t)(m0 + r0 + srow) * K + kbeg + swst, &As[0][r0][0]);
      gload_lds16(B + (size_t)(n0 + r0 + srow) * K + kbeg + swst, &Bs[0][r0][0]);
    }
  }
  for (int it = 0; it < niter; ++it) {
    __syncthreads();
    if (it + 1 < niter) {
      const int kk = kbeg + (it + 1) * 64;
      const int nb = (it + 1) & 1;
#pragma unroll
      for (int j = 0; j < 4; ++j) {
        int r0 = 8 * (w * 4 + j);
        gload_lds16(A + (size_t)(m0 + r0 + srow) * K + kk + swst, &As[nb][r0][0]);
        gload_lds16(B + (size_t)(n0 + r0 + srow) * K + kk + swst, &Bs[nb][r0][0]);
      }
    }
    const int cb = it & 1;
    half8 af[4][2], bf[4][2];
#pragma unroll
    for (int kk2 = 0; kk2 < 2; ++kk2) {
      const int sw = ((kk2 * 4 + (L >> 4)) ^ (L & 7)) * 8;
#pragma unroll
      for (int t = 0; t < 4; ++t) {
        af[t][kk2] = *reinterpret_cast<const half8*>(&As[cb][mq + t * 16 + (L & 15)][sw]);
        bf[t][kk2] = *reinterpret_cast<const half8*>(&Bs[cb][nq + t * 16 + (L & 15)][sw]);
      }
    }
#pragma unroll
    for (int kk2 = 0; kk2 < 2; ++kk2)
#pragma unroll
      for (int mt = 0; mt < 4; ++mt)
#pragma unroll
        for (int nt = 0; nt < 4; ++nt)
          acc[mt][nt] = __builtin_amdgcn_mfma_f32_16x16x32_f16(af[mt][kk2], bf[nt][kk2],
                                                               acc[mt][nt], 0, 0, 0);
  }
  const int qrow = (L >> 4) * 4;
#pragma unroll
  for (int mt = 0; mt < 4; ++mt) {
#pragma unroll
    for (int nt = 0; nt < 4; ++nt) {
      int col = n0 + nq + nt * 16 + (L & 15);
#pragma unroll
      for (int r = 0; r < 4; ++r) {
        int row = m0 + mq + mt * 16 + qrow + r;
        C[(size_t)row * N + col] = acc[mt][nt][r];
      }
    }
  }
}

// ---------------- reduce 4 out_proj partials + bias ----------------
__global__ __launch_bounds__(256) void reduce_out4(const float* __restrict__ p,
                                                   const float* __restrict__ bias,
                                                   float* __restrict__ out, int MN) {
  int i = blockIdx.x * 256 + threadIdx.x;
  if (i * 4 >= MN) return;
  float4 a = reinterpret_cast<const float4*>(p)[i];
  float4 b = reinterpret_cast<const float4*>(p + MN)[i];
  float4 c = reinterpret_cast<const float4*>(p + 2 * (size_t)MN)[i];
  float4 d = reinterpret_cast<const float4*>(p + 3 * (size_t)MN)[i];
  int col = (i * 4) & (HID - 1);
  float4 bv = *reinterpret_cast<const float4*>(bias + col);
  float4 o;
  o.x = a.x + b.x + c.x + d.x + bv.x;
  o.y = a.y + b.y + c.y + d.y + bv.y;
  o.z = a.z + b.z + c.z + d.z + bv.z;
  o.w = a.w + b.w + c.w + d.w + bv.w;
  reinterpret_cast<float4*>(out)[i] = o;
}

// ---------------- per-token pointwise: dt, g (transposed), level scales ----------------
// zxf holds pre-biased f32 cols [4352,4864): [dt(32) | dl(480)]
__global__ __launch_bounds__(512) void pointwise_dt(
    const float* __restrict__ zxf, const float* __restrict__ dt_bias,
    const float* __restrict__ A_log, const float* __restrict__ L_param,
    float* __restrict__ dtbuf, float* __restrict__ gT,
    float* __restrict__ Lsbuf) {
  const int t = blockIdx.x;
  const int j = threadIdx.x;
  const size_t ro = (size_t)t * NPROJF;
  if (j < NHEAD * NLVL) {
    float x = L_param[j] * zxf[ro + NHEAD + j];
    Lsbuf[(size_t)t * (NHEAD * NLVL) + j] = softplus_f(x);
  } else {
    int h = j - NHEAD * NLVL;
    float x = zxf[ro + h] + dt_bias[h];
    float dt = softplus_f(x);
    dtbuf[t * NHEAD + h] = dt;
    gT[h * T_LEN + t] = -expf(A_log[h]) * dt;   // transposed for the scan
  }
}

// ---------------- per-head fp64 scan, wave-shuffle (no barriers) ----------------
// grid = 32 heads, block = 64 lanes; lane l owns t in [l*16, l*16+16)
__global__ __launch_bounds__(64) void scan_g(const float* __restrict__ gT,
                                             double* __restrict__ cgd) {
  const int h = blockIdx.x, l = threadIdx.x;
  const float* gr = gT + (size_t)h * T_LEN + l * 16;
  double pre[16];
  double acc = 0.0;
#pragma unroll
  for (int i = 0; i < 16; ++i) { acc += (double)gr[i]; pre[i] = acc; }
  double s = acc;
#pragma unroll
  for (int off = 1; off < 64; off <<= 1) {
    double o = __shfl_up(s, off, 64);
    if (l >= off) s += o;
  }
  const double base = s - acc;   // exclusive prefix of lane totals
  double* cr = cgd + (size_t)h * T_LEN + l * 16;
#pragma unroll
  for (int i = 0; i < 16; ++i) cr[i] = base + pre[i];
}

// ---------------- fused conv(K=4)+SiLU+split, with in-block V transpose ----------------
// grid (16 t-tiles, 36 c-tiles of 64). c-tile<32: v path (head = cy); else B/C.
// xBC read from zxh (f16, pre-biased) at cols [INTER, INTER+CONV_DIM)
__global__ __launch_bounds__(256) void conv_fused(
    const ushort_t* __restrict__ zxh, const float* __restrict__ conv_w,
    const float* __restrict__ dtbuf, const float* __restrict__ Dp,
    ushort_t* __restrict__ vt, float* __restrict__ ybuf,
    ushort_t* __restrict__ Bb, ushort_t* __restrict__ Cb) {
  __shared__ ushort_t Vl[64][68];
  __shared__ float dtl[64];
  const int tq = blockIdx.x, cy = blockIdx.y;
  const int t0 = tq * 64;
  const int tid = threadIdx.x;
  const int lane = tid & 63, g = tid >> 6;
  const bool vpath = (cy < 32);
  const int ccol = vpath ? cy * 64 + lane : INTER + (cy - 32) * 64 + lane;  // conv-dim idx
  const int zcol = INTER + ccol;   // column in zxh
  float cw[KCONV];
#pragma unroll
  for (int w = 0; w < KCONV; ++w) cw[w] = conv_w[ccol * KCONV + w];
  if (vpath && tid < 64) dtl[tid] = dtbuf[(t0 + tid) * NHEAD + cy];
  const float Dh = vpath ? Dp[cy] : 0.f;

  float xv[19];
#pragma unroll
  for (int i = 0; i < 19; ++i) {
    int tt = t0 + g * 16 - 3 + i;
    if (tt >= 0) {
      xv[i] = h2f(zxh[(size_t)tt * NPROJ16 + zcol]);
    } else xv[i] = 0.f;
  }
  __syncthreads();   // dtl ready
#pragma unroll
  for (int i = 0; i < 16; ++i) {
    float acc = xv[i] * cw[0] + xv[i + 1] * cw[1] + xv[i + 2] * cw[2] + xv[i + 3] * cw[3];
    float sil = silu_f(acc);
    int tl = g * 16 + i;
    int t = t0 + tl;
    if (vpath) {
      ushort_t vh = f2h(sil * dtl[tl]);
      Vl[tl][lane] = vh;                                       // for transpose
      ybuf[(size_t)t * INTER + cy * 64 + lane] = sil * Dh;     // D residual
    } else if (ccol < INTER + NSTATE) {
      Bb[t * NSTATE + (ccol - INTER)] = f2h(sil);
    } else {
      Cb[t * NSTATE + (ccol - INTER - NSTATE)] = f2h(sil);
    }
  }
  if (vpath) {
    __syncthreads();
#pragma unroll
    for (int rep = 0; rep < 2; ++rep) {
      int u = tid + 256 * rep;
      int p = u >> 3, t8 = (u & 7) * 8;
      union { ushort_t u16[8]; half8 h; } o;
#pragma unroll
      for (int j = 0; j < 8; ++j) o.u16[j] = Vl[t8 + j][p];
      *reinterpret_cast<half8*>(vt + (size_t)(cy * 64 + p) * T_LEN + t0 + t8) = o.h;
    }
  }
}

// ---------------- head-independent QK^T (G=1): S = C . B^T, causal 64-tiles only -------
// grid = 136 blocks (pairs (qt,st), st<=qt), 256 threads, no LDS (C/B are L2-resident).
__global__ __launch_bounds__(256) void qk_gemm(
    const ushort_t* __restrict__ Cq, const ushort_t* __restrict__ Bk,
    ushort_t* __restrict__ S) {
  const int idx = blockIdx.x;
  int qt = (int)(0.5f * (sqrtf(8.f * (float)idx + 1.f) - 1.f));
  if ((qt + 1) * (qt + 2) / 2 <= idx) ++qt;
  if (qt * (qt + 1) / 2 > idx) --qt;
  const int st = idx - qt * (qt + 1) / 2;
  const int tid = threadIdx.x, w = tid >> 6, L = tid & 63;
  const int q0 = qt * 64 + (w & 1) * 32;
  const int s0 = st * 64 + (w >> 1) * 32;

  half8 af[2][4], bf[2][4];
#pragma unroll
  for (int mt = 0; mt < 2; ++mt)
#pragma unroll
    for (int ks = 0; ks < 4; ++ks) {
      af[mt][ks] = *reinterpret_cast<const half8*>(
          Cq + (size_t)(q0 + mt * 16 + (L & 15)) * NSTATE + ks * 32 + (L >> 4) * 8);
      bf[mt][ks] = *reinterpret_cast<const half8*>(
          Bk + (size_t)(s0 + mt * 16 + (L & 15)) * NSTATE + ks * 32 + (L >> 4) * 8);
    }
  float4v acc[2][2];
#pragma unroll
  for (int i = 0; i < 2; ++i)
#pragma unroll
    for (int j = 0; j < 2; ++j) acc[i][j] = (float4v){0.f, 0.f, 0.f, 0.f};
#pragma unroll
  for (int ks = 0; ks < 4; ++ks)
#pragma unroll
    for (int mt = 0; mt < 2; ++mt)
#pragma unroll
      for (int nt = 0; nt < 2; ++nt)
        acc[mt][nt] = __builtin_amdgcn_mfma_f32_16x16x32_f16(af[mt][ks], bf[nt][ks],
                                                             acc[mt][nt], 0, 0, 0);
  const int qrow = (L >> 4) * 4;
#pragma unroll
  for (int mt = 0; mt < 2; ++mt)
#pragma unroll
    for (int nt = 0; nt < 2; ++nt) {
      int col = s0 + nt * 16 + (L & 15);
#pragma unroll
      for (int r = 0; r < 4; ++r)
        S[(size_t)(q0 + mt * 16 + qrow + r) * T_LEN + col] = f2h(acc[mt][nt][r]);
    }
}

// ---------------- split-K MFMA attention (PV only; S precomputed) ----------------
__global__ __launch_bounds__(256) void attn_mfma(
    const ushort_t* __restrict__ S, const ushort_t* __restrict__ vt,
    const double* __restrict__ cgd, const float* __restrict__ Lsb,
    float* __restrict__ ybuf) {
  __shared__ ushort_t Vtl[64][72];
  __shared__ float Lsl[64][17];
  __shared__ __align__(16) float cgq[64];
  __shared__ __align__(16) float cgs[64];

  const int item = blockIdx.x;
  const int h = item / 40;
  const int rem = item - h * 40;
  int qt, j;
  if (rem < 4)        { qt = rem;                 j = 0; }
  else if (rem < 12)  { qt = 4 + (rem - 4) / 2;   j = (rem - 4) % 2; }
  else if (rem < 24)  { qt = 8 + (rem - 12) / 3;  j = (rem - 12) % 3; }
  else                { qt = 12 + (rem - 24) / 4; j = (rem - 24) % 4; }

  const int tid = threadIdx.x;
  const int w = tid >> 6, L = tid & 63;
  const int tq0 = qt * 64;
  const double* cgh = cgd + (size_t)h * T_LEN;
  const double base = cgh[tq0];

  for (int i = tid; i < 64 * NLVL; i += 256) {
    int r = i / NLVL, l = i - r * NLVL;
    Lsl[r][l] = Lsb[(size_t)(tq0 + r) * (NHEAD * NLVL) + h * NLVL + l];
  }
  if (tid < 64) cgq[tid] = (float)(cgh[tq0 + tid] - base);

  float4v yac[4];
#pragma unroll
  for (int i = 0; i < 4; ++i) yac[i] = (float4v){0.f, 0.f, 0.f, 0.f};

  const int qloc = w * 16 + (L & 15);   // this lane's A-frag row (local q)
  const int tg = tq0 + qloc;
  const int qrow = w * 16 + ((L >> 4) << 2);   // D-layout row base for epilogue

  const int st0 = 4 * j;
  const int st1 = min(4 * j + 4, qt + 1);
  for (int st = st0; st < st1; ++st) {
    const int ts0 = st * 64;
    __syncthreads();
    // issue S loads early (L2) to hide under Vtl staging
    half8 sv0 = *reinterpret_cast<const half8*>(
        S + (size_t)tg * T_LEN + ts0 + (L >> 4) * 8);
    half8 sv1 = *reinterpret_cast<const half8*>(
        S + (size_t)tg * T_LEN + ts0 + 32 + (L >> 4) * 8);
#pragma unroll
    for (int i = 0; i < 2; ++i) {
      int u = tid + 256 * i;
      int p = u >> 3, sc = (u & 7) * 8;
      *reinterpret_cast<half8*>(&Vtl[p][sc]) =
          *reinterpret_cast<const half8*>(vt + (size_t)(h * HDIM + p) * T_LEN + ts0 + sc);
    }
    if (tid < 64) cgs[tid] = (float)(cgh[ts0 + tid] - base);
    __syncthreads();

    const float cq = cgq[qloc];
    half8 af[2];
#pragma unroll
    for (int ks = 0; ks < 2; ++ks) {
      const half8 sv = ks ? sv1 : sv0;
      const int sb = ks * 32 + (L >> 4) * 8;
      float4 c0 = *reinterpret_cast<const float4*>(&cgs[sb]);
      float4 c1 = *reinterpret_cast<const float4*>(&cgs[sb + 4]);
      float csv[8] = {c0.x, c0.y, c0.z, c0.w, c1.x, c1.y, c1.z, c1.w};
      union { ushort_t u[8]; half8 h; } o;
#pragma unroll
      for (int jj = 0; jj < 8; ++jj) {
        int sg = ts0 + sb + jj;
        float val = 0.f;
        if (sg <= tg) {
          int lvl = 31 - __clz((unsigned)(sg ^ (tg + 1)));
          val = (float)sv[jj] * __expf(cq - csv[jj]) * Lsl[qloc][lvl];
        }
        o.u[jj] = f2h(val);
      }
      af[ks] = o.h;
    }
#pragma unroll
    for (int ks = 0; ks < 2; ++ks) {
#pragma unroll
      for (int pt = 0; pt < 4; ++pt) {
        half8 bfv = *reinterpret_cast<const half8*>(&Vtl[pt * 16 + (L & 15)][ks * 32 + (L >> 4) * 8]);
        yac[pt] = __builtin_amdgcn_mfma_f32_16x16x32_f16(af[ks], bfv, yac[pt], 0, 0, 0);
      }
    }
  }
#pragma unroll
  for (int pt = 0; pt < 4; ++pt) {
    int p = pt * 16 + (L & 15);
#pragma unroll
    for (int r = 0; r < 4; ++r) {
      int q = qrow + r;
      atomicAdd(ybuf + (size_t)(tq0 + q) * INTER + h * HDIM + p, yac[pt][r]);
    }
  }
}

// ---------------- gated RMSNorm -> f16 ----------------
// z read from zxh (f16, pre-biased) at cols [0, INTER)
__global__ __launch_bounds__(256) void rmsnorm_gate(
    const float* __restrict__ ybuf, const ushort_t* __restrict__ zxh,
    const float* __restrict__ w, ushort_t* __restrict__ yhf) {
  __shared__ float red[4];
  const int t = blockIdx.x, tid = threadIdx.x;
  const size_t ro = (size_t)t * NPROJ16;
  const float* yrow = ybuf + (size_t)t * INTER;
  float yg[8];
  float ss = 0.f;
#pragma unroll
  for (int i = 0; i < 8; ++i) {
    int c = tid + 256 * i;
    float z = h2f(zxh[ro + c]);
    float g = yrow[c] * silu_f(z);
    yg[i] = g;
    ss += g * g;
  }
#pragma unroll
  for (int off = 32; off; off >>= 1) ss += __shfl_down(ss, off, 64);
  if ((tid & 63) == 0) red[tid >> 6] = ss;
  __syncthreads();
  if (tid == 0) red[0] = red[0] + red[1] + red[2] + red[3];
  __syncthreads();
  const float scale = rsqrtf(red[0] / (float)INTER + EPS);
#pragma unroll
  for (int i = 0; i < 8; ++i) {
    int c = tid + 256 * i;
    yhf[(size_t)t * INTER + c] = f2h(yg[i] * scale * w[c]);
  }
}

// ---------------- launch ----------------
extern "C" void kernel_launch(void* const* d_in, const int* in_sizes, int n_in,
                              void* d_out, int out_size, void* d_ws, size_t ws_size,
                              hipStream_t stream) {
  const float* hs        = (const float*)d_in[0];
  const float* in_proj_w = (const float*)d_in[1];
  const float* in_proj_b = (const float*)d_in[2];
  const float* conv_w    = (const float*)d_in[3];
  const float* dt_bias   = (const float*)d_in[4];
  const float* A_log     = (const float*)d_in[5];
  const float* L_param   = (const float*)d_in[6];
  const float* Dp        = (const float*)d_in[7];
  const float* rms_w     = (const float*)d_in[8];
  const float* out_proj_w= (const float*)d_in[9];
  const float* out_proj_b= (const float*)d_in[10];
  float* out = (float*)d_out;

  char* W = (char*)d_ws;
  size_t off = 0;
  auto alloc = [&](size_t bytes) { void* p = W + off; off = (off + bytes + 255) & ~(size_t)255; return p; };
  double*   cgd = (double*)  alloc((size_t)NHEAD * T_LEN * 8);
  float*    zxf = (float*)   alloc((size_t)T_LEN * NPROJF * 4);
  float*    opp = (float*)   alloc((size_t)4 * T_LEN * HID * 4);
  float*    ybuf= (float*)   alloc((size_t)T_LEN * INTER * 4);
  float*    gT  = (float*)   alloc((size_t)NHEAD * T_LEN * 4);
  float*    dtb = (float*)   alloc((size_t)T_LEN * NHEAD * 4);
  float*    Lsb = (float*)   alloc((size_t)T_LEN * NHEAD * NLVL * 4);
  ushort_t* zxh = (ushort_t*)alloc((size_t)T_LEN * NPROJ16 * 2);
  ushort_t* hsb = (ushort_t*)alloc((size_t)T_LEN * HID * 2);
  ushort_t* Wib = (ushort_t*)alloc((size_t)PROJ * HID * 2);
  ushort_t* Wob = (ushort_t*)alloc((size_t)HID * INTER * 2);
  ushort_t* yhf = (ushort_t*)alloc((size_t)T_LEN * INTER * 2);
  ushort_t* vt  = (ushort_t*)alloc((size_t)T_LEN * INTER * 2);
  ushort_t* Bb  = (ushort_t*)alloc((size_t)T_LEN * NSTATE * 2);
  ushort_t* Cb  = (ushort_t*)alloc((size_t)T_LEN * NSTATE * 2);
  ushort_t* Sbuf= (ushort_t*)alloc((size_t)T_LEN * T_LEN * 2);

  // 1. fused f32->f16 conversions (hs, in_proj_w, out_proj_w)
  prep_f16<<<(N4_HS + N4_WI + N4_WO) / 256, 256, 0, stream>>>(
      hs, in_proj_w, out_proj_w, hsb, Wib, Wob);

  // 2. in_proj GEMM: 128x128 tiles, BK=64, bias folded, mixed f16/f32 output
  gemm_in<<<dim3(PROJ / 128, T_LEN / 128), 256, 0, stream>>>(
      hsb, Wib, in_proj_b, zxh, zxf);

  // 3. pointwise (g written transposed)
  pointwise_dt<<<T_LEN, 512, 0, stream>>>(zxf, dt_bias, A_log, L_param, dtb, gT, Lsb);

  // 4. fp64 wave-shuffle scan
  scan_g<<<NHEAD, 64, 0, stream>>>(gT, cgd);

  // 5. fused conv + silu + split + V transpose
  conv_fused<<<dim3(T_LEN / 64, 36), 256, 0, stream>>>(
      zxh, conv_w, dtb, Dp, vt, ybuf, Bb, Cb);

  // 6a. head-independent QK^T once (G=1)
  qk_gemm<<<136, 256, 0, stream>>>(Cb, Bb, Sbuf);

  // 6b. split-K MFMA attention (PV only)
  attn_mfma<<<NHEAD * 40, 256, 0, stream>>>(Sbuf, vt, cgd, Lsb, ybuf);

  // 7. gated RMSNorm -> f16
  rmsnorm_gate<<<T_LEN, 256, 0, stream>>>(ybuf, zxh, rms_w, yhf);

  // 8. out_proj split-K=4 -> partials, then reduce(+bias)
  gemm_f16_sk<<<dim3(HID / 128, T_LEN / 128, 4), 256, 0, stream>>>(
      yhf, Wob, opp, T_LEN, HID, INTER, INTER / 4);
  reduce_out4<<<(T_LEN * HID / 4 + 255) / 256, 256, 0, stream>>>(
      opp, out_proj_b, out, T_LEN * HID);
}